// Round 1
// baseline (358.531 us; speedup 1.0000x reference)
//
#include <hip/hip_runtime.h>
#include <math.h>
#include <stdint.h>

#define D_MODEL 1024
#define NHEADS  16
#define DK      64
#define BATCH   4
#define SEQ     2048
#define MROWS   (BATCH * SEQ)              // 8192
#define TENS    ((size_t)MROWS * D_MODEL)  // 8.39M elems
#define WELT    ((size_t)D_MODEL * D_MODEL)

typedef __attribute__((ext_vector_type(8))) _Float16 f16x8;
typedef __attribute__((ext_vector_type(2))) __fp16 h16x2;
typedef __attribute__((ext_vector_type(4))) float f32x4;
typedef __attribute__((ext_vector_type(8))) unsigned short us8;
typedef __attribute__((ext_vector_type(4))) unsigned short us4;

__device__ __forceinline__ unsigned short f2h(float x) {
    _Float16 h = (_Float16)x;
    return __builtin_bit_cast(unsigned short, h);
}

#if __has_builtin(__builtin_amdgcn_exp2f)
__device__ __forceinline__ float fexp2(float x) { return __builtin_amdgcn_exp2f(x); }
#else
__device__ __forceinline__ float fexp2(float x) { return exp2f(x); }
#endif

// async global->LDS, 16B per lane; LDS dst is wave-uniform base + lane*16
__device__ __forceinline__ void gld_lds16(const void* g, void* l) {
    __builtin_amdgcn_global_load_lds(
        (__attribute__((address_space(1))) void*)(uintptr_t)(g),
        (__attribute__((address_space(3))) void*)(unsigned)(uintptr_t)(l),
        16, 0, 0);
}

// ---------------------------------------------------------------------------
// fp32 -> f16 conversion of all inputs into workspace.
// seg 0..2: Q/K/V tensors (TENS each). seg 3: all four weight matrices
// (dst contiguous; src selected by i>>20). Trims ~25K empty blocks vs the
// old 7-segment grid.
// ---------------------------------------------------------------------------
__global__ __launch_bounds__(256)
void convert_kernel(const float* __restrict__ q, const float* __restrict__ k,
                    const float* __restrict__ v, const float* __restrict__ wq,
                    const float* __restrict__ wk, const float* __restrict__ wv,
                    const float* __restrict__ wo, unsigned short* __restrict__ dst)
{
    const int seg = blockIdx.y;
    size_t i = ((size_t)blockIdx.x * 256 + threadIdx.x) * 4;
    const float* src;
    size_t doff, soff;
    if (seg < 3) {
        if (i >= TENS) return;
        src = (seg == 0) ? q : (seg == 1) ? k : v;
        soff = i;
        doff = (size_t)seg * TENS + i;
    } else {
        if (i >= 4 * WELT) return;
        const int widx = (int)(i >> 20);          // WELT == 1<<20
        src = (widx == 0) ? wq : (widx == 1) ? wk : (widx == 2) ? wv : wo;
        soff = i & (WELT - 1);
        doff = 3 * TENS + i;
    }
    float4 f = *(const float4*)(src + soff);
    us4 o = { f2h(f.x), f2h(f.y), f2h(f.z), f2h(f.w) };
    *(us4*)(dst + doff) = o;
}

// ---------------------------------------------------------------------------
// f16 MFMA NT GEMM body: C[M,N] = A[M,K] @ B[N,K]^T
// 128x128 tile, 256 thr = 4 waves, BK=64, global_load_lds(16B), XOR swizzle.
// omode: 0 = fp32 row-major, 1 = f16 row-major, 2 = f16 transposed [b,h,d,s]
// ---------------------------------------------------------------------------
__device__ __forceinline__
void gemm_body(const unsigned short* __restrict__ A,
               const unsigned short* __restrict__ B,
               void* __restrict__ C, int N, int K, int omode,
               unsigned short* As, unsigned short* Bs)
{
    const int tid  = threadIdx.x;
    const int wave = tid >> 6;
    const int lane = tid & 63;
    const int g    = lane >> 4;
    const int m15  = lane & 15;
    const int bm   = blockIdx.x * 128;
    const int bn   = blockIdx.y * 128;

    const int srw = lane >> 3;
    const int lc  = (lane & 7) ^ srw;

    const int wr = (wave >> 1) * 64;
    const int wc = (wave & 1) * 64;

    f32x4 acc[4][4];
#pragma unroll
    for (int i = 0; i < 4; ++i)
#pragma unroll
        for (int j = 0; j < 4; ++j) acc[i][j] = (f32x4){0.f, 0.f, 0.f, 0.f};

    for (int k0 = 0; k0 < K; k0 += 64) {
        __syncthreads();
#pragma unroll
        for (int i = 0; i < 4; ++i) {
            const int rb = wave * 32 + i * 8;
            gld_lds16(A + (size_t)(bm + rb + srw) * K + k0 + lc * 8,
                      &As[rb * 64]);
            gld_lds16(B + (size_t)(bn + rb + srw) * K + k0 + lc * 8,
                      &Bs[rb * 64]);
        }
        __syncthreads();

#pragma unroll
        for (int t = 0; t < 2; ++t) {
            f16x8 af[4], bf[4];
#pragma unroll
            for (int i = 0; i < 4; ++i) {
                int row = wr + i * 16 + m15;
                int pc  = (4 * t + g) ^ (row & 7);
                af[i] = *(const f16x8*)&As[row * 64 + pc * 8];
            }
#pragma unroll
            for (int j = 0; j < 4; ++j) {
                int row = wc + j * 16 + m15;
                int pc  = (4 * t + g) ^ (row & 7);
                bf[j] = *(const f16x8*)&Bs[row * 64 + pc * 8];
            }
#pragma unroll
            for (int i = 0; i < 4; ++i)
#pragma unroll
                for (int j = 0; j < 4; ++j)
                    acc[i][j] = __builtin_amdgcn_mfma_f32_16x16x32_f16(
                        af[i], bf[j], acc[i][j], 0, 0, 0);
        }
    }

#pragma unroll
    for (int i = 0; i < 4; ++i) {
        const int gm0 = bm + wr + i * 16 + g * 4;
#pragma unroll
        for (int j = 0; j < 4; ++j) {
            const int gn = bn + wc + j * 16 + m15;
            if (omode == 0) {
#pragma unroll
                for (int r = 0; r < 4; ++r)
                    ((float*)C)[(size_t)(gm0 + r) * N + gn] = acc[i][j][r];
            } else if (omode == 1) {
#pragma unroll
                for (int r = 0; r < 4; ++r)
                    ((unsigned short*)C)[(size_t)(gm0 + r) * N + gn] = f2h(acc[i][j][r]);
            } else {
                const int b_ = gm0 >> 11, s_ = gm0 & 2047;
                const int h_ = gn >> 6,  d_ = gn & 63;
                us4 o = { f2h(acc[i][j][0]), f2h(acc[i][j][1]),
                          f2h(acc[i][j][2]), f2h(acc[i][j][3]) };
                *(us4*)((unsigned short*)C +
                        (((size_t)(b_ * NHEADS + h_) * DK + d_) << 11) + s_) = o;
            }
        }
    }
}

// Fused Q/K/V projections in one dispatch: blockIdx.z selects the GEMM.
__global__ __launch_bounds__(256)
void proj3_kernel(const unsigned short* __restrict__ qb,
                  const unsigned short* __restrict__ kb,
                  const unsigned short* __restrict__ vb,
                  const unsigned short* __restrict__ wq,
                  const unsigned short* __restrict__ wk,
                  const unsigned short* __restrict__ wv,
                  unsigned short* __restrict__ qproj,
                  unsigned short* __restrict__ kproj,
                  unsigned short* __restrict__ vtw)
{
    __shared__ unsigned short As[128 * 64];
    __shared__ unsigned short Bs[128 * 64];
    const int z = blockIdx.z;
    const unsigned short* A = (z == 0) ? qb : (z == 1) ? kb : vb;
    const unsigned short* B = (z == 0) ? wq : (z == 1) ? wk : wv;
    void* C = (z == 0) ? (void*)qproj : (z == 1) ? (void*)kproj : (void*)vtw;
    gemm_body(A, B, C, D_MODEL, D_MODEL, (z == 2) ? 2 : 1, As, Bs);
}

__global__ __launch_bounds__(256)
void gemm_out_kernel(const unsigned short* __restrict__ A,
                     const unsigned short* __restrict__ B,
                     float* __restrict__ C)
{
    __shared__ unsigned short As[128 * 64];
    __shared__ unsigned short Bs[128 * 64];
    gemm_body(A, B, C, D_MODEL, D_MODEL, 0, As, Bs);
}

// ---------------------------------------------------------------------------
// Flash attention, transposed-score form, 32 q/wave (mi=2).
// Grid (SEQ/128, NHEADS, BATCH) = 1024 blocks, 256 thr = 4 waves;
// wave w owns 32 q-rows -> 4 blocks/CU resident (occupancy fix: was 2).
// K-tile = 64 keys.  S^T = K·Q^T (A=K LDS, B=Q regs, log2-domain pre-scale);
// register online softmax (2 shuffles per reduce, exp2);
// O^T = V^T·P^T (A=V^T LDS, B=P^T per-wave LDS round-trip, XOR-swizzled).
// qp,kp: [B,S,D_MODEL] f16; vt: [B,H,DK,S] f16; ao: [B,S,D_MODEL] f16
// ---------------------------------------------------------------------------
__global__ __launch_bounds__(256, 4)
void attn_kernel(const unsigned short* __restrict__ qp,
                 const unsigned short* __restrict__ kp,
                 const unsigned short* __restrict__ vt,
                 unsigned short* __restrict__ ao)
{
    __shared__ unsigned short Ks[64 * 64];     // [key][d], XOR-swizzled
    __shared__ unsigned short VTs[64 * 64];    // [d][key], XOR-swizzled
    __shared__ unsigned short Ps[4][32 * 64];  // per-wave P^T [q][key], XOR-swizzled

    const int tid = threadIdx.x;
    const int w = tid >> 6, lane = tid & 63;
    const int g = lane >> 4, m15 = lane & 15;
    const int qt = blockIdx.x, h = blockIdx.y, b = blockIdx.z;

    const int q0 = qt * 128 + w * 32;
    const size_t rowbase = (size_t)b * SEQ;

    const int srw = lane >> 3;
    const int lc  = (lane & 7) ^ srw;

    // Q fragments (B-operand), pre-scaled by (1/sqrt(dk)) * log2(e)
    const _Float16 qscale = (_Float16)(0.125f * 1.4426950408889634f);
    f16x8 qf[2][2];
#pragma unroll
    for (int mi = 0; mi < 2; ++mi)
#pragma unroll
        for (int t = 0; t < 2; ++t) {
            f16x8 v = *(const f16x8*)(qp + (rowbase + q0 + mi * 16 + m15) * D_MODEL
                                      + h * DK + t * 32 + g * 8);
            qf[mi][t] = v * qscale;
        }

    float mrun[2] = {-INFINITY, -INFINITY};
    float lrun[2] = {0.f, 0.f};

    f32x4 accO[2][4];
#pragma unroll
    for (int mi = 0; mi < 2; ++mi)
#pragma unroll
        for (int i = 0; i < 4; ++i) accO[mi][i] = (f32x4){0.f, 0.f, 0.f, 0.f};

    const unsigned short* kbase = kp + rowbase * D_MODEL + h * DK;
    const unsigned short* vbase = vt + (size_t)(b * NHEADS + h) * DK * SEQ;

    for (int kt = 0; kt < SEQ / 64; ++kt) {
        __syncthreads();   // prior iteration's Ks/VTs reads complete
#pragma unroll
        for (int it = 0; it < 2; ++it) {
            const int rb = w * 16 + it * 8;
            gld_lds16(kbase + (size_t)(kt * 64 + rb + srw) * D_MODEL + lc * 8,
                      &Ks[rb * 64]);
            gld_lds16(vbase + (size_t)(rb + srw) * SEQ + kt * 64 + lc * 8,
                      &VTs[rb * 64]);
        }
        __syncthreads();

        // S^T (log2 domain): ST[km][mi] reg r: key=km*16+g*4+r, q=mi*16+m15
        f32x4 ST[4][2];
        __builtin_amdgcn_s_setprio(1);
#pragma unroll
        for (int km = 0; km < 4; ++km) {
            const int row = km * 16 + m15;
            f16x8 kf0 = *(const f16x8*)&Ks[row * 64 + ((0 + g) ^ (row & 7)) * 8];
            f16x8 kf1 = *(const f16x8*)&Ks[row * 64 + ((4 + g) ^ (row & 7)) * 8];
#pragma unroll
            for (int mi = 0; mi < 2; ++mi) {
                f32x4 z = (f32x4){0.f, 0.f, 0.f, 0.f};
                z = __builtin_amdgcn_mfma_f32_16x16x32_f16(kf0, qf[mi][0], z, 0, 0, 0);
                z = __builtin_amdgcn_mfma_f32_16x16x32_f16(kf1, qf[mi][1], z, 0, 0, 0);
                ST[km][mi] = z;
            }
        }
        __builtin_amdgcn_s_setprio(0);

        // register-resident online softmax in log2 domain (q = mi*16+m15)
        float scl[2];
#pragma unroll
        for (int mi = 0; mi < 2; ++mi) {
            const int prow = mi * 16 + m15;
            float mx = -INFINITY;
#pragma unroll
            for (int km = 0; km < 4; ++km)
#pragma unroll
                for (int r = 0; r < 4; ++r) mx = fmaxf(mx, ST[km][mi][r]);
            mx = fmaxf(mx, __shfl_xor(mx, 16));
            mx = fmaxf(mx, __shfl_xor(mx, 32));
            float mnew = fmaxf(mrun[mi], mx);
            scl[mi] = fexp2(mrun[mi] - mnew);
            mrun[mi] = mnew;
            float rs = 0.f;
#pragma unroll
            for (int km = 0; km < 4; ++km) {
                float p0 = fexp2(ST[km][mi][0] - mnew);
                float p1 = fexp2(ST[km][mi][1] - mnew);
                float p2 = fexp2(ST[km][mi][2] - mnew);
                float p3 = fexp2(ST[km][mi][3] - mnew);
                rs += (p0 + p1) + (p2 + p3);
                h16x2 d0 = __builtin_amdgcn_cvt_pkrtz(p0, p1);
                h16x2 d1 = __builtin_amdgcn_cvt_pkrtz(p2, p3);
                uint2 wv = { __builtin_bit_cast(unsigned, d0),
                             __builtin_bit_cast(unsigned, d1) };
                // write 8B at linear col km*16+g*4, chunk-XOR-swizzled
                const int pc = (km * 2 + (g >> 1)) ^ (prow & 7);
                *(uint2*)&Ps[w][prow * 64 + pc * 8 + (g & 1) * 4] = wv;
            }
            rs += __shfl_xor(rs, 16);
            rs += __shfl_xor(rs, 32);
            lrun[mi] = lrun[mi] * scl[mi] + rs;
        }

        // wave-uniform skip of accO rescale when max didn't move anywhere
        int chg = (scl[0] < 1.f) | (scl[1] < 1.f);
        if (__any(chg)) {
#pragma unroll
            for (int mi = 0; mi < 2; ++mi)
#pragma unroll
                for (int i = 0; i < 4; ++i) accO[mi][i] *= scl[mi];
        }

        // P^T B-frags (per-wave LDS, intra-wave ordering only), same XOR scheme
        f16x8 pf[2][2];
#pragma unroll
        for (int mi = 0; mi < 2; ++mi) {
            const int prow = mi * 16 + m15;
            pf[mi][0] = *(const f16x8*)&Ps[w][prow * 64 + ((0 + g) ^ (prow & 7)) * 8];
            pf[mi][1] = *(const f16x8*)&Ps[w][prow * 64 + ((4 + g) ^ (prow & 7)) * 8];
        }

        // O^T += V^T·P^T
        __builtin_amdgcn_s_setprio(1);
#pragma unroll
        for (int i = 0; i < 4; ++i) {
            const int row = i * 16 + m15;
            f16x8 vf0 = *(const f16x8*)&VTs[row * 64 + ((0 + g) ^ (row & 7)) * 8];
            f16x8 vf1 = *(const f16x8*)&VTs[row * 64 + ((4 + g) ^ (row & 7)) * 8];
#pragma unroll
            for (int mi = 0; mi < 2; ++mi) {
                f32x4 a = accO[mi][i];
                a = __builtin_amdgcn_mfma_f32_16x16x32_f16(vf0, pf[mi][0], a, 0, 0, 0);
                a = __builtin_amdgcn_mfma_f32_16x16x32_f16(vf1, pf[mi][1], a, 0, 0, 0);
                accO[mi][i] = a;
            }
        }
        __builtin_amdgcn_s_setprio(0);
    }

    // epilogue: O^T row d=i*16+g*4+r, col q=mi*16+m15 -> ao[b][s][h*64+d]
#pragma unroll
    for (int mi = 0; mi < 2; ++mi) {
        const float li = 1.f / lrun[mi];
        const size_t qg = rowbase + q0 + mi * 16 + m15;
#pragma unroll
        for (int i = 0; i < 4; ++i) {
            us4 o = { f2h(accO[mi][i][0] * li), f2h(accO[mi][i][1] * li),
                      f2h(accO[mi][i][2] * li), f2h(accO[mi][i][3] * li) };
            *(us4*)(ao + qg * D_MODEL + h * DK + i * 16 + g * 4) = o;
        }
    }
}

// ---------------------------------------------------------------------------
extern "C" void kernel_launch(void* const* d_in, const int* in_sizes, int n_in,
                              void* d_out, int out_size, void* d_ws, size_t ws_size,
                              hipStream_t stream)
{
    const float* Q  = (const float*)d_in[0];
    const float* K  = (const float*)d_in[1];
    const float* V  = (const float*)d_in[2];
    const float* Wq = (const float*)d_in[3];
    const float* Wk = (const float*)d_in[4];
    const float* Wv = (const float*)d_in[5];
    const float* Wo = (const float*)d_in[6];

    unsigned short* base = (unsigned short*)d_ws;
    unsigned short* qb = base;
    unsigned short* kb = qb + TENS;
    unsigned short* vb = kb + TENS;
    unsigned short* wq = vb + TENS;
    unsigned short* wk = wq + WELT;
    unsigned short* wv = wk + WELT;
    unsigned short* wo = wv + WELT;
    unsigned short* qproj = wo + WELT;
    unsigned short* kproj = qproj + TENS;
    unsigned short* vtw   = kproj + TENS;    // [B,H,DK,S]
    unsigned short* aow   = vtw + TENS;

    convert_kernel<<<dim3(TENS / 1024, 4), 256, 0, stream>>>(Q, K, V, Wq, Wk, Wv, Wo, base);

    proj3_kernel<<<dim3(MROWS / 128, D_MODEL / 128, 3), 256, 0, stream>>>(
        qb, kb, vb, wq, wk, wv, qproj, kproj, vtw);

    attn_kernel<<<dim3(SEQ / 128, NHEADS, BATCH), 256, 0, stream>>>(
        qproj, kproj, vtw, aow);

    gemm_out_kernel<<<dim3(MROWS / 128, D_MODEL / 128), 256, 0, stream>>>(
        aow, wo, (float*)d_out);
}

// Round 2
// 346.459 us; speedup vs baseline: 1.0348x; 1.0348x over previous
//
#include <hip/hip_runtime.h>
#include <math.h>
#include <stdint.h>

#define D_MODEL 1024
#define NHEADS  16
#define DK      64
#define BATCH   4
#define SEQ     2048
#define MROWS   (BATCH * SEQ)              // 8192
#define TENS    ((size_t)MROWS * D_MODEL)  // 8.39M elems
#define WELT    ((size_t)D_MODEL * D_MODEL)

typedef __attribute__((ext_vector_type(8))) _Float16 f16x8;
typedef __attribute__((ext_vector_type(2))) __fp16 h16x2;
typedef __attribute__((ext_vector_type(4))) float f32x4;
typedef __attribute__((ext_vector_type(8))) unsigned short us8;
typedef __attribute__((ext_vector_type(4))) unsigned short us4;

__device__ __forceinline__ unsigned short f2h(float x) {
    _Float16 h = (_Float16)x;
    return __builtin_bit_cast(unsigned short, h);
}

#if __has_builtin(__builtin_amdgcn_exp2f)
__device__ __forceinline__ float fexp2(float x) { return __builtin_amdgcn_exp2f(x); }
#else
__device__ __forceinline__ float fexp2(float x) { return exp2f(x); }
#endif

// async global->LDS, 16B per lane; LDS dst is wave-uniform base + lane*16
__device__ __forceinline__ void gld_lds16(const void* g, void* l) {
    __builtin_amdgcn_global_load_lds(
        (__attribute__((address_space(1))) void*)(uintptr_t)(g),
        (__attribute__((address_space(3))) void*)(unsigned)(uintptr_t)(l),
        16, 0, 0);
}

// ---------------------------------------------------------------------------
// fp32 -> f16 conversion of all inputs into workspace.
// seg 0..2: Q/K/V tensors (TENS each). seg 3: all four weight matrices.
// ---------------------------------------------------------------------------
__global__ __launch_bounds__(256)
void convert_kernel(const float* __restrict__ q, const float* __restrict__ k,
                    const float* __restrict__ v, const float* __restrict__ wq,
                    const float* __restrict__ wk, const float* __restrict__ wv,
                    const float* __restrict__ wo, unsigned short* __restrict__ dst)
{
    const int seg = blockIdx.y;
    size_t i = ((size_t)blockIdx.x * 256 + threadIdx.x) * 4;
    const float* src;
    size_t doff, soff;
    if (seg < 3) {
        if (i >= TENS) return;
        src = (seg == 0) ? q : (seg == 1) ? k : v;
        soff = i;
        doff = (size_t)seg * TENS + i;
    } else {
        if (i >= 4 * WELT) return;
        const int widx = (int)(i >> 20);          // WELT == 1<<20
        src = (widx == 0) ? wq : (widx == 1) ? wk : (widx == 2) ? wv : wo;
        soff = i & (WELT - 1);
        doff = 3 * TENS + i;
    }
    float4 f = *(const float4*)(src + soff);
    us4 o = { f2h(f.x), f2h(f.y), f2h(f.z), f2h(f.w) };
    *(us4*)(dst + doff) = o;
}

// ---------------------------------------------------------------------------
// f16 MFMA NT GEMM body: C[M,N] = A[M,K] @ B[N,K]^T
// 128x128 tile, 256 thr = 4 waves, BK=64, global_load_lds(16B), XOR swizzle.
// omode: 0 = fp32 row-major, 1 = f16 row-major, 2 = f16 transposed [b,h,d,s]
// ---------------------------------------------------------------------------
__device__ __forceinline__
void gemm_body(const unsigned short* __restrict__ A,
               const unsigned short* __restrict__ B,
               void* __restrict__ C, int N, int K, int omode,
               unsigned short* As, unsigned short* Bs)
{
    const int tid  = threadIdx.x;
    const int wave = tid >> 6;
    const int lane = tid & 63;
    const int g    = lane >> 4;
    const int m15  = lane & 15;
    const int bm   = blockIdx.x * 128;
    const int bn   = blockIdx.y * 128;

    const int srw = lane >> 3;
    const int lc  = (lane & 7) ^ srw;

    const int wr = (wave >> 1) * 64;
    const int wc = (wave & 1) * 64;

    f32x4 acc[4][4];
#pragma unroll
    for (int i = 0; i < 4; ++i)
#pragma unroll
        for (int j = 0; j < 4; ++j) acc[i][j] = (f32x4){0.f, 0.f, 0.f, 0.f};

    for (int k0 = 0; k0 < K; k0 += 64) {
        __syncthreads();
#pragma unroll
        for (int i = 0; i < 4; ++i) {
            const int rb = wave * 32 + i * 8;
            gld_lds16(A + (size_t)(bm + rb + srw) * K + k0 + lc * 8,
                      &As[rb * 64]);
            gld_lds16(B + (size_t)(bn + rb + srw) * K + k0 + lc * 8,
                      &Bs[rb * 64]);
        }
        __syncthreads();

#pragma unroll
        for (int t = 0; t < 2; ++t) {
            f16x8 af[4], bf[4];
#pragma unroll
            for (int i = 0; i < 4; ++i) {
                int row = wr + i * 16 + m15;
                int pc  = (4 * t + g) ^ (row & 7);
                af[i] = *(const f16x8*)&As[row * 64 + pc * 8];
            }
#pragma unroll
            for (int j = 0; j < 4; ++j) {
                int row = wc + j * 16 + m15;
                int pc  = (4 * t + g) ^ (row & 7);
                bf[j] = *(const f16x8*)&Bs[row * 64 + pc * 8];
            }
#pragma unroll
            for (int i = 0; i < 4; ++i)
#pragma unroll
                for (int j = 0; j < 4; ++j)
                    acc[i][j] = __builtin_amdgcn_mfma_f32_16x16x32_f16(
                        af[i], bf[j], acc[i][j], 0, 0, 0);
        }
    }

#pragma unroll
    for (int i = 0; i < 4; ++i) {
        const int gm0 = bm + wr + i * 16 + g * 4;
#pragma unroll
        for (int j = 0; j < 4; ++j) {
            const int gn = bn + wc + j * 16 + m15;
            if (omode == 0) {
#pragma unroll
                for (int r = 0; r < 4; ++r)
                    ((float*)C)[(size_t)(gm0 + r) * N + gn] = acc[i][j][r];
            } else if (omode == 1) {
#pragma unroll
                for (int r = 0; r < 4; ++r)
                    ((unsigned short*)C)[(size_t)(gm0 + r) * N + gn] = f2h(acc[i][j][r]);
            } else {
                const int b_ = gm0 >> 11, s_ = gm0 & 2047;
                const int h_ = gn >> 6,  d_ = gn & 63;
                us4 o = { f2h(acc[i][j][0]), f2h(acc[i][j][1]),
                          f2h(acc[i][j][2]), f2h(acc[i][j][3]) };
                *(us4*)((unsigned short*)C +
                        (((size_t)(b_ * NHEADS + h_) * DK + d_) << 11) + s_) = o;
            }
        }
    }
}

// Fused Q/K/V projections in one dispatch: blockIdx.z selects the GEMM.
__global__ __launch_bounds__(256)
void proj3_kernel(const unsigned short* __restrict__ qb,
                  const unsigned short* __restrict__ kb,
                  const unsigned short* __restrict__ vb,
                  const unsigned short* __restrict__ wq,
                  const unsigned short* __restrict__ wk,
                  const unsigned short* __restrict__ wv,
                  unsigned short* __restrict__ qproj,
                  unsigned short* __restrict__ kproj,
                  unsigned short* __restrict__ vtw)
{
    __shared__ unsigned short As[128 * 64];
    __shared__ unsigned short Bs[128 * 64];
    const int z = blockIdx.z;
    const unsigned short* A = (z == 0) ? qb : (z == 1) ? kb : vb;
    const unsigned short* B = (z == 0) ? wq : (z == 1) ? wk : wv;
    void* C = (z == 0) ? (void*)qproj : (z == 1) ? (void*)kproj : (void*)vtw;
    gemm_body(A, B, C, D_MODEL, D_MODEL, (z == 2) ? 2 : 1, As, Bs);
}

__global__ __launch_bounds__(256)
void gemm_out_kernel(const unsigned short* __restrict__ A,
                     const unsigned short* __restrict__ B,
                     float* __restrict__ C)
{
    __shared__ unsigned short As[128 * 64];
    __shared__ unsigned short Bs[128 * 64];
    gemm_body(A, B, C, D_MODEL, D_MODEL, 0, As, Bs);
}

// ---------------------------------------------------------------------------
// Flash attention, transposed-score form, 64 q/wave (mi=4), 2-phase pipeline.
// Grid (SEQ/256, NHEADS, BATCH), 256 thr = 4 waves; wave w owns 64 q-rows.
// K-tile = 64 keys, DOUBLE-BUFFERED: next tile's global_load_lds issued
// BEFORE computing current tile; single __syncthreads() per tile at the
// bottom (its vmcnt(0) drain lands after ~1500 cy of compute -> HBM latency
// hidden, was fully exposed in the old sync/stage/sync/compute form).
// S^T = K·Q^T (A=K LDS, B=Q regs, log2-domain pre-scale);
// register online softmax (2 shuffles per reduce, exp2);
// O^T = V^T·P^T; P^T round-trips per-mi through a 16-row per-wave LDS
// buffer (in-order LDS FIFO makes reuse across mi safe without sync).
// qp,kp: [B,S,D_MODEL] f16; vt: [B,H,DK,S] f16; ao: [B,S,D_MODEL] f16
// ---------------------------------------------------------------------------
__global__ __launch_bounds__(256, 2)
void attn_kernel(const unsigned short* __restrict__ qp,
                 const unsigned short* __restrict__ kp,
                 const unsigned short* __restrict__ vt,
                 unsigned short* __restrict__ ao)
{
    __shared__ unsigned short Ks[2][64 * 64];   // [buf][key][d], XOR-swizzled
    __shared__ unsigned short VTs[2][64 * 64];  // [buf][d][key], XOR-swizzled
    __shared__ unsigned short Ps[4][16 * 72];   // per-wave P^T, one mi at a time, padded

    const int tid = threadIdx.x;
    const int w = tid >> 6, lane = tid & 63;
    const int g = lane >> 4, m15 = lane & 15;
    const int qt = blockIdx.x, h = blockIdx.y, b = blockIdx.z;

    const int q0 = qt * 256 + w * 64;
    const size_t rowbase = (size_t)b * SEQ;

    const int srw = lane >> 3;
    const int lc  = (lane & 7) ^ srw;

    // Q fragments (B-operand), pre-scaled by (1/sqrt(dk)) * log2(e)
    const _Float16 qscale = (_Float16)(0.125f * 1.4426950408889634f);
    f16x8 qf[4][2];
#pragma unroll
    for (int mi = 0; mi < 4; ++mi)
#pragma unroll
        for (int t = 0; t < 2; ++t) {
            f16x8 v = *(const f16x8*)(qp + (rowbase + q0 + mi * 16 + m15) * D_MODEL
                                      + h * DK + t * 32 + g * 8);
            qf[mi][t] = v * qscale;
        }

    float mrun[4] = {-INFINITY, -INFINITY, -INFINITY, -INFINITY};
    float lrun[4] = {0.f, 0.f, 0.f, 0.f};

    f32x4 accO[4][4];
#pragma unroll
    for (int mi = 0; mi < 4; ++mi)
#pragma unroll
        for (int i = 0; i < 4; ++i) accO[mi][i] = (f32x4){0.f, 0.f, 0.f, 0.f};

    const unsigned short* kbase = kp + rowbase * D_MODEL + h * DK;
    const unsigned short* vbase = vt + (size_t)(b * NHEADS + h) * DK * SEQ;

    auto stage = [&](int buf, int t) {
#pragma unroll
        for (int it = 0; it < 2; ++it) {
            const int rb = w * 16 + it * 8;
            gld_lds16(kbase + (size_t)(t * 64 + rb + srw) * D_MODEL + lc * 8,
                      &Ks[buf][rb * 64]);
            gld_lds16(vbase + (size_t)(rb + srw) * SEQ + t * 64 + lc * 8,
                      &VTs[buf][rb * 64]);
        }
    };

    const int NT = SEQ / 64;
    stage(0, 0);
    __syncthreads();   // compiler-emitted vmcnt(0) drains prologue loads

    for (int kt = 0; kt < NT; ++kt) {
        const int cur = kt & 1;
        if (kt + 1 < NT) stage(cur ^ 1, kt + 1);   // prefetch overlaps compute below

        // S^T (log2 domain): ST[km][mi] reg r: key=km*16+g*4+r, q=mi*16+m15
        f32x4 ST[4][4];
        __builtin_amdgcn_s_setprio(1);
#pragma unroll
        for (int km = 0; km < 4; ++km) {
            const int row = km * 16 + m15;
            f16x8 kf0 = *(const f16x8*)&Ks[cur][row * 64 + ((0 + g) ^ (row & 7)) * 8];
            f16x8 kf1 = *(const f16x8*)&Ks[cur][row * 64 + ((4 + g) ^ (row & 7)) * 8];
#pragma unroll
            for (int mi = 0; mi < 4; ++mi) {
                f32x4 z = (f32x4){0.f, 0.f, 0.f, 0.f};
                z = __builtin_amdgcn_mfma_f32_16x16x32_f16(kf0, qf[mi][0], z, 0, 0, 0);
                z = __builtin_amdgcn_mfma_f32_16x16x32_f16(kf1, qf[mi][1], z, 0, 0, 0);
                ST[km][mi] = z;
            }
        }
        __builtin_amdgcn_s_setprio(0);

        // register-resident online softmax in log2 domain (q = mi*16+m15).
        // P^T round-trip fused per-mi through 16-row per-wave LDS buffer.
        float scl[4];
        f16x8 pf[4][2];
#pragma unroll
        for (int mi = 0; mi < 4; ++mi) {
            float mx = -INFINITY;
#pragma unroll
            for (int km = 0; km < 4; ++km)
#pragma unroll
                for (int r = 0; r < 4; ++r) mx = fmaxf(mx, ST[km][mi][r]);
            mx = fmaxf(mx, __shfl_xor(mx, 16));
            mx = fmaxf(mx, __shfl_xor(mx, 32));
            float mnew = fmaxf(mrun[mi], mx);
            scl[mi] = fexp2(mrun[mi] - mnew);
            mrun[mi] = mnew;
            float rs = 0.f;
#pragma unroll
            for (int km = 0; km < 4; ++km) {
                float p0 = fexp2(ST[km][mi][0] - mnew);
                float p1 = fexp2(ST[km][mi][1] - mnew);
                float p2 = fexp2(ST[km][mi][2] - mnew);
                float p3 = fexp2(ST[km][mi][3] - mnew);
                rs += (p0 + p1) + (p2 + p3);
                h16x2 d0 = __builtin_amdgcn_cvt_pkrtz(p0, p1);
                h16x2 d1 = __builtin_amdgcn_cvt_pkrtz(p2, p3);
                uint2 wv = { __builtin_bit_cast(unsigned, d0),
                             __builtin_bit_cast(unsigned, d1) };
                *(uint2*)&Ps[w][m15 * 72 + km * 16 + g * 4] = wv;
            }
            rs += __shfl_xor(rs, 16);
            rs += __shfl_xor(rs, 32);
            lrun[mi] = lrun[mi] * scl[mi] + rs;
            // read back this mi's P^T fragments (in-order LDS FIFO: safe)
            pf[mi][0] = *(const f16x8*)&Ps[w][m15 * 72 + g * 8];
            pf[mi][1] = *(const f16x8*)&Ps[w][m15 * 72 + 32 + g * 8];
        }

        // wave-uniform skip of accO rescale when max didn't move anywhere
        int chg = (scl[0] < 1.f) | (scl[1] < 1.f) | (scl[2] < 1.f) | (scl[3] < 1.f);
        if (__any(chg)) {
#pragma unroll
            for (int mi = 0; mi < 4; ++mi)
#pragma unroll
                for (int i = 0; i < 4; ++i) accO[mi][i] *= scl[mi];
        }

        // O^T += V^T·P^T
        __builtin_amdgcn_s_setprio(1);
#pragma unroll
        for (int i = 0; i < 4; ++i) {
            const int row = i * 16 + m15;
            f16x8 vf0 = *(const f16x8*)&VTs[cur][row * 64 + ((0 + g) ^ (row & 7)) * 8];
            f16x8 vf1 = *(const f16x8*)&VTs[cur][row * 64 + ((4 + g) ^ (row & 7)) * 8];
#pragma unroll
            for (int mi = 0; mi < 4; ++mi) {
                f32x4 a = accO[mi][i];
                a = __builtin_amdgcn_mfma_f32_16x16x32_f16(vf0, pf[mi][0], a, 0, 0, 0);
                a = __builtin_amdgcn_mfma_f32_16x16x32_f16(vf1, pf[mi][1], a, 0, 0, 0);
                accO[mi][i] = a;
            }
        }
        __builtin_amdgcn_s_setprio(0);

        __syncthreads();   // drains vmcnt(0) (prefetch done) + protects buffer reuse
    }

    // epilogue: O^T row d=i*16+g*4+r, col q=mi*16+m15 -> ao[b][s][h*64+d]
#pragma unroll
    for (int mi = 0; mi < 4; ++mi) {
        const float li = 1.f / lrun[mi];
        const size_t qg = rowbase + q0 + mi * 16 + m15;
#pragma unroll
        for (int i = 0; i < 4; ++i) {
            us4 o = { f2h(accO[mi][i][0] * li), f2h(accO[mi][i][1] * li),
                      f2h(accO[mi][i][2] * li), f2h(accO[mi][i][3] * li) };
            *(us4*)(ao + qg * D_MODEL + h * DK + i * 16 + g * 4) = o;
        }
    }
}

// ---------------------------------------------------------------------------
extern "C" void kernel_launch(void* const* d_in, const int* in_sizes, int n_in,
                              void* d_out, int out_size, void* d_ws, size_t ws_size,
                              hipStream_t stream)
{
    const float* Q  = (const float*)d_in[0];
    const float* K  = (const float*)d_in[1];
    const float* V  = (const float*)d_in[2];
    const float* Wq = (const float*)d_in[3];
    const float* Wk = (const float*)d_in[4];
    const float* Wv = (const float*)d_in[5];
    const float* Wo = (const float*)d_in[6];

    unsigned short* base = (unsigned short*)d_ws;
    unsigned short* qb = base;
    unsigned short* kb = qb + TENS;
    unsigned short* vb = kb + TENS;
    unsigned short* wq = vb + TENS;
    unsigned short* wk = wq + WELT;
    unsigned short* wv = wk + WELT;
    unsigned short* wo = wv + WELT;
    unsigned short* qproj = wo + WELT;
    unsigned short* kproj = qproj + TENS;
    unsigned short* vtw   = kproj + TENS;    // [B,H,DK,S]
    unsigned short* aow   = vtw + TENS;

    convert_kernel<<<dim3(TENS / 1024, 4), 256, 0, stream>>>(Q, K, V, Wq, Wk, Wv, Wo, base);

    proj3_kernel<<<dim3(MROWS / 128, D_MODEL / 128, 3), 256, 0, stream>>>(
        qb, kb, vb, wq, wk, wv, qproj, kproj, vtw);

    attn_kernel<<<dim3(SEQ / 256, NHEADS, BATCH), 256, 0, stream>>>(
        qproj, kproj, vtw, aow);

    gemm_out_kernel<<<dim3(MROWS / 128, D_MODEL / 128), 256, 0, stream>>>(
        aow, wo, (float*)d_out);
}

// Round 3
// 344.243 us; speedup vs baseline: 1.0415x; 1.0064x over previous
//
#include <hip/hip_runtime.h>
#include <math.h>
#include <stdint.h>

#define D_MODEL 1024
#define NHEADS  16
#define DK      64
#define BATCH   4
#define SEQ     2048
#define MROWS   (BATCH * SEQ)              // 8192
#define TENS    ((size_t)MROWS * D_MODEL)  // 8.39M elems
#define WELT    ((size_t)D_MODEL * D_MODEL)

typedef __attribute__((ext_vector_type(8))) _Float16 f16x8;
typedef __attribute__((ext_vector_type(2))) __fp16 h16x2;
typedef __attribute__((ext_vector_type(4))) float f32x4;
typedef __attribute__((ext_vector_type(8))) unsigned short us8;
typedef __attribute__((ext_vector_type(4))) unsigned short us4;

__device__ __forceinline__ unsigned short f2h(float x) {
    _Float16 h = (_Float16)x;
    return __builtin_bit_cast(unsigned short, h);
}

#if __has_builtin(__builtin_amdgcn_exp2f)
__device__ __forceinline__ float fexp2(float x) { return __builtin_amdgcn_exp2f(x); }
#else
__device__ __forceinline__ float fexp2(float x) { return exp2f(x); }
#endif

// async global->LDS, 16B per lane; LDS dst is wave-uniform base + lane*16
__device__ __forceinline__ void gld_lds16(const void* g, void* l) {
    __builtin_amdgcn_global_load_lds(
        (__attribute__((address_space(1))) void*)(uintptr_t)(g),
        (__attribute__((address_space(3))) void*)(unsigned)(uintptr_t)(l),
        16, 0, 0);
}

// ---------------------------------------------------------------------------
// fp32 -> f16 conversion of all inputs into workspace.
// seg 0..2: Q/K/V tensors (TENS each). seg 3: all four weight matrices.
// ---------------------------------------------------------------------------
__global__ __launch_bounds__(256)
void convert_kernel(const float* __restrict__ q, const float* __restrict__ k,
                    const float* __restrict__ v, const float* __restrict__ wq,
                    const float* __restrict__ wk, const float* __restrict__ wv,
                    const float* __restrict__ wo, unsigned short* __restrict__ dst)
{
    const int seg = blockIdx.y;
    size_t i = ((size_t)blockIdx.x * 256 + threadIdx.x) * 4;
    const float* src;
    size_t doff, soff;
    if (seg < 3) {
        if (i >= TENS) return;
        src = (seg == 0) ? q : (seg == 1) ? k : v;
        soff = i;
        doff = (size_t)seg * TENS + i;
    } else {
        if (i >= 4 * WELT) return;
        const int widx = (int)(i >> 20);          // WELT == 1<<20
        src = (widx == 0) ? wq : (widx == 1) ? wk : (widx == 2) ? wv : wo;
        soff = i & (WELT - 1);
        doff = 3 * TENS + i;
    }
    float4 f = *(const float4*)(src + soff);
    us4 o = { f2h(f.x), f2h(f.y), f2h(f.z), f2h(f.w) };
    *(us4*)(dst + doff) = o;
}

// ---------------------------------------------------------------------------
// f16 MFMA NT GEMM body: C[M,N] = A[M,K] @ B[N,K]^T
// 128x128 tile, 256 thr = 4 waves, BK=64, global_load_lds(16B), XOR swizzle.
// omode: 0 = fp32 row-major, 1 = f16 row-major,
//        2 = f16 V-transpose, granule-interleaved [b][h][s/8][d][s%8]
//            (4 consecutive s per us4 store -> two dense 256B tx per
//             wave-store instead of 64 scattered 8B pieces at 4KB stride)
// ---------------------------------------------------------------------------
__device__ __forceinline__
void gemm_body(const unsigned short* __restrict__ A,
               const unsigned short* __restrict__ B,
               void* __restrict__ C, int N, int K, int omode,
               unsigned short* As, unsigned short* Bs)
{
    const int tid  = threadIdx.x;
    const int wave = tid >> 6;
    const int lane = tid & 63;
    const int g    = lane >> 4;
    const int m15  = lane & 15;
    const int bm   = blockIdx.x * 128;
    const int bn   = blockIdx.y * 128;

    const int srw = lane >> 3;
    const int lc  = (lane & 7) ^ srw;

    const int wr = (wave >> 1) * 64;
    const int wc = (wave & 1) * 64;

    f32x4 acc[4][4];
#pragma unroll
    for (int i = 0; i < 4; ++i)
#pragma unroll
        for (int j = 0; j < 4; ++j) acc[i][j] = (f32x4){0.f, 0.f, 0.f, 0.f};

    for (int k0 = 0; k0 < K; k0 += 64) {
        __syncthreads();
#pragma unroll
        for (int i = 0; i < 4; ++i) {
            const int rb = wave * 32 + i * 8;
            gld_lds16(A + (size_t)(bm + rb + srw) * K + k0 + lc * 8,
                      &As[rb * 64]);
            gld_lds16(B + (size_t)(bn + rb + srw) * K + k0 + lc * 8,
                      &Bs[rb * 64]);
        }
        __syncthreads();

#pragma unroll
        for (int t = 0; t < 2; ++t) {
            f16x8 af[4], bf[4];
#pragma unroll
            for (int i = 0; i < 4; ++i) {
                int row = wr + i * 16 + m15;
                int pc  = (4 * t + g) ^ (row & 7);
                af[i] = *(const f16x8*)&As[row * 64 + pc * 8];
            }
#pragma unroll
            for (int j = 0; j < 4; ++j) {
                int row = wc + j * 16 + m15;
                int pc  = (4 * t + g) ^ (row & 7);
                bf[j] = *(const f16x8*)&Bs[row * 64 + pc * 8];
            }
#pragma unroll
            for (int i = 0; i < 4; ++i)
#pragma unroll
                for (int j = 0; j < 4; ++j)
                    acc[i][j] = __builtin_amdgcn_mfma_f32_16x16x32_f16(
                        af[i], bf[j], acc[i][j], 0, 0, 0);
        }
    }

#pragma unroll
    for (int i = 0; i < 4; ++i) {
        const int gm0 = bm + wr + i * 16 + g * 4;
#pragma unroll
        for (int j = 0; j < 4; ++j) {
            const int gn = bn + wc + j * 16 + m15;
            if (omode == 0) {
#pragma unroll
                for (int r = 0; r < 4; ++r)
                    ((float*)C)[(size_t)(gm0 + r) * N + gn] = acc[i][j][r];
            } else if (omode == 1) {
#pragma unroll
                for (int r = 0; r < 4; ++r)
                    ((unsigned short*)C)[(size_t)(gm0 + r) * N + gn] = f2h(acc[i][j][r]);
            } else {
                const int b_ = gm0 >> 11, s_ = gm0 & 2047;
                const int h_ = gn >> 6,  d_ = gn & 63;
                us4 o = { f2h(acc[i][j][0]), f2h(acc[i][j][1]),
                          f2h(acc[i][j][2]), f2h(acc[i][j][3]) };
                // [b][h][s>>3][d][s&7]; s_&7 in {0,4} so the us4 is 8B-aligned
                *(us4*)((unsigned short*)C +
                        (((size_t)(b_ * NHEADS + h_) * 256 + (s_ >> 3)) * 64 + d_) * 8
                        + (s_ & 7)) = o;
            }
        }
    }
}

// Fused Q/K/V projections in one dispatch: blockIdx.z selects the GEMM.
__global__ __launch_bounds__(256)
void proj3_kernel(const unsigned short* __restrict__ qb,
                  const unsigned short* __restrict__ kb,
                  const unsigned short* __restrict__ vb,
                  const unsigned short* __restrict__ wq,
                  const unsigned short* __restrict__ wk,
                  const unsigned short* __restrict__ wv,
                  unsigned short* __restrict__ qproj,
                  unsigned short* __restrict__ kproj,
                  unsigned short* __restrict__ vtw)
{
    __shared__ unsigned short As[128 * 64];
    __shared__ unsigned short Bs[128 * 64];
    const int z = blockIdx.z;
    const unsigned short* A = (z == 0) ? qb : (z == 1) ? kb : vb;
    const unsigned short* B = (z == 0) ? wq : (z == 1) ? wk : wv;
    void* C = (z == 0) ? (void*)qproj : (z == 1) ? (void*)kproj : (void*)vtw;
    gemm_body(A, B, C, D_MODEL, D_MODEL, (z == 2) ? 2 : 1, As, Bs);
}

__global__ __launch_bounds__(256)
void gemm_out_kernel(const unsigned short* __restrict__ A,
                     const unsigned short* __restrict__ B,
                     float* __restrict__ C)
{
    __shared__ unsigned short As[128 * 64];
    __shared__ unsigned short Bs[128 * 64];
    gemm_body(A, B, C, D_MODEL, D_MODEL, 0, As, Bs);
}

// ---------------------------------------------------------------------------
// Flash attention, transposed-score form, 64 q/wave (mi=4), 2-phase pipeline.
// Grid (SEQ/256, NHEADS, BATCH), 256 thr = 4 waves; wave w owns 64 q-rows.
// K-tile = 64 keys, double-buffered (prefetch before compute, one barrier).
// S^T = K·Q^T (log2-domain pre-scale); register online softmax;
// softmax DENOMINATOR via ones-vector MFMA on the P^T fragments
// (mfma(ones, pf) -> C[i][q=m15] = rowsum; replaces 15 adds + 2 shuffles
// per mi with 2 MFMA on the 25%-utilized matrix pipe).
// O^T = V^T·P^T; P^T round-trips per-mi through 16-row per-wave LDS FIFO.
// qp,kp: [B,S,D_MODEL] f16; vt: [B,H,S/8,DK,8] f16 (granule-interleaved);
// ao: [B,S,D_MODEL] f16
// ---------------------------------------------------------------------------
__global__ __launch_bounds__(256, 2)
void attn_kernel(const unsigned short* __restrict__ qp,
                 const unsigned short* __restrict__ kp,
                 const unsigned short* __restrict__ vt,
                 unsigned short* __restrict__ ao)
{
    __shared__ unsigned short Ks[2][64 * 64];   // [buf][key][d], XOR-swizzled
    __shared__ unsigned short VTs[2][64 * 64];  // [buf][d][key], XOR-swizzled
    __shared__ unsigned short Ps[4][16 * 72];   // per-wave P^T, one mi at a time

    const int tid = threadIdx.x;
    const int w = tid >> 6, lane = tid & 63;
    const int g = lane >> 4, m15 = lane & 15;
    const int qt = blockIdx.x, h = blockIdx.y, b = blockIdx.z;

    const int q0 = qt * 256 + w * 64;
    const size_t rowbase = (size_t)b * SEQ;

    const int srw = lane >> 3;
    const int lc  = (lane & 7) ^ srw;

    // Q fragments (B-operand), pre-scaled by (1/sqrt(dk)) * log2(e)
    const _Float16 qscale = (_Float16)(0.125f * 1.4426950408889634f);
    f16x8 qf[4][2];
#pragma unroll
    for (int mi = 0; mi < 4; ++mi)
#pragma unroll
        for (int t = 0; t < 2; ++t) {
            f16x8 v = *(const f16x8*)(qp + (rowbase + q0 + mi * 16 + m15) * D_MODEL
                                      + h * DK + t * 32 + g * 8);
            qf[mi][t] = v * qscale;
        }

    const _Float16 one16 = (_Float16)1.f;
    const f16x8 onesf = { one16, one16, one16, one16, one16, one16, one16, one16 };

    float mrun[4] = {-INFINITY, -INFINITY, -INFINITY, -INFINITY};
    float lrun[4] = {0.f, 0.f, 0.f, 0.f};

    f32x4 accO[4][4];
#pragma unroll
    for (int mi = 0; mi < 4; ++mi)
#pragma unroll
        for (int i = 0; i < 4; ++i) accO[mi][i] = (f32x4){0.f, 0.f, 0.f, 0.f};

    const unsigned short* kbase = kp + rowbase * D_MODEL + h * DK;
    const unsigned short* vbase = vt + (size_t)(b * NHEADS + h) * DK * SEQ;

    auto stage = [&](int buf, int t) {
#pragma unroll
        for (int it = 0; it < 2; ++it) {
            const int rb = w * 16 + it * 8;
            gld_lds16(kbase + (size_t)(t * 64 + rb + srw) * D_MODEL + lc * 8,
                      &Ks[buf][rb * 64]);
            // vt granule layout: elem = (s8*64 + d)*8 + (s&7); 16B = 8 s for one d
            gld_lds16(vbase + ((size_t)(t * 8 + lc) * 64 + rb + srw) * 8,
                      &VTs[buf][rb * 64]);
        }
    };

    const int NT = SEQ / 64;
    stage(0, 0);
    __syncthreads();   // compiler-emitted vmcnt(0) drains prologue loads

    for (int kt = 0; kt < NT; ++kt) {
        const int cur = kt & 1;
        if (kt + 1 < NT) stage(cur ^ 1, kt + 1);   // prefetch overlaps compute below

        // S^T (log2 domain): ST[km][mi] reg r: key=km*16+g*4+r, q=mi*16+m15
        f32x4 ST[4][4];
        __builtin_amdgcn_s_setprio(1);
#pragma unroll
        for (int km = 0; km < 4; ++km) {
            const int row = km * 16 + m15;
            f16x8 kf0 = *(const f16x8*)&Ks[cur][row * 64 + ((0 + g) ^ (row & 7)) * 8];
            f16x8 kf1 = *(const f16x8*)&Ks[cur][row * 64 + ((4 + g) ^ (row & 7)) * 8];
#pragma unroll
            for (int mi = 0; mi < 4; ++mi) {
                f32x4 z = (f32x4){0.f, 0.f, 0.f, 0.f};
                z = __builtin_amdgcn_mfma_f32_16x16x32_f16(kf0, qf[mi][0], z, 0, 0, 0);
                z = __builtin_amdgcn_mfma_f32_16x16x32_f16(kf1, qf[mi][1], z, 0, 0, 0);
                ST[km][mi] = z;
            }
        }
        __builtin_amdgcn_s_setprio(0);

        // register-resident online softmax in log2 domain (q = mi*16+m15).
        // max via v_max3-fusable triples; denominator via ones-MFMA below.
        float scl[4];
        f16x8 pf[4][2];
#pragma unroll
        for (int mi = 0; mi < 4; ++mi) {
            float t0 = fmaxf(fmaxf(ST[0][mi][0], ST[0][mi][1]), ST[0][mi][2]);
            float t1 = fmaxf(fmaxf(ST[0][mi][3], ST[1][mi][0]), ST[1][mi][1]);
            float t2 = fmaxf(fmaxf(ST[1][mi][2], ST[1][mi][3]), ST[2][mi][0]);
            float t3 = fmaxf(fmaxf(ST[2][mi][1], ST[2][mi][2]), ST[2][mi][3]);
            float t4 = fmaxf(fmaxf(ST[3][mi][0], ST[3][mi][1]), ST[3][mi][2]);
            float u0 = fmaxf(fmaxf(t0, t1), t2);
            float u1 = fmaxf(fmaxf(t3, t4), ST[3][mi][3]);
            float mx = fmaxf(u0, u1);
            mx = fmaxf(mx, __shfl_xor(mx, 16));
            mx = fmaxf(mx, __shfl_xor(mx, 32));
            float mnew = fmaxf(mrun[mi], mx);
            scl[mi] = fexp2(mrun[mi] - mnew);
            mrun[mi] = mnew;
#pragma unroll
            for (int km = 0; km < 4; ++km) {
                float p0 = fexp2(ST[km][mi][0] - mnew);
                float p1 = fexp2(ST[km][mi][1] - mnew);
                float p2 = fexp2(ST[km][mi][2] - mnew);
                float p3 = fexp2(ST[km][mi][3] - mnew);
                h16x2 d0 = __builtin_amdgcn_cvt_pkrtz(p0, p1);
                h16x2 d1 = __builtin_amdgcn_cvt_pkrtz(p2, p3);
                uint2 wv = { __builtin_bit_cast(unsigned, d0),
                             __builtin_bit_cast(unsigned, d1) };
                *(uint2*)&Ps[w][m15 * 72 + km * 16 + g * 4] = wv;
            }
            // read back this mi's P^T fragments (in-order LDS FIFO: safe)
            pf[mi][0] = *(const f16x8*)&Ps[w][m15 * 72 + g * 8];
            pf[mi][1] = *(const f16x8*)&Ps[w][m15 * 72 + 32 + g * 8];
            // denominator on the matrix pipe: C[i][q=m15] = sum_k P^T[q][k]
            f32x4 zs = (f32x4){0.f, 0.f, 0.f, 0.f};
            zs = __builtin_amdgcn_mfma_f32_16x16x32_f16(onesf, pf[mi][0], zs, 0, 0, 0);
            zs = __builtin_amdgcn_mfma_f32_16x16x32_f16(onesf, pf[mi][1], zs, 0, 0, 0);
            lrun[mi] = lrun[mi] * scl[mi] + zs[0];
        }

        // wave-uniform skip of accO rescale when max didn't move anywhere
        int chg = (scl[0] < 1.f) | (scl[1] < 1.f) | (scl[2] < 1.f) | (scl[3] < 1.f);
        if (__any(chg)) {
#pragma unroll
            for (int mi = 0; mi < 4; ++mi)
#pragma unroll
                for (int i = 0; i < 4; ++i) accO[mi][i] *= scl[mi];
        }

        // O^T += V^T·P^T
        __builtin_amdgcn_s_setprio(1);
#pragma unroll
        for (int i = 0; i < 4; ++i) {
            const int row = i * 16 + m15;
            f16x8 vf0 = *(const f16x8*)&VTs[cur][row * 64 + ((0 + g) ^ (row & 7)) * 8];
            f16x8 vf1 = *(const f16x8*)&VTs[cur][row * 64 + ((4 + g) ^ (row & 7)) * 8];
#pragma unroll
            for (int mi = 0; mi < 4; ++mi) {
                f32x4 a = accO[mi][i];
                a = __builtin_amdgcn_mfma_f32_16x16x32_f16(vf0, pf[mi][0], a, 0, 0, 0);
                a = __builtin_amdgcn_mfma_f32_16x16x32_f16(vf1, pf[mi][1], a, 0, 0, 0);
                accO[mi][i] = a;
            }
        }
        __builtin_amdgcn_s_setprio(0);

        __syncthreads();   // drains vmcnt(0) (prefetch done) + protects buffer reuse
    }

    // epilogue: O^T row d=i*16+g*4+r, col q=mi*16+m15 -> ao[b][s][h*64+d]
#pragma unroll
    for (int mi = 0; mi < 4; ++mi) {
        const float li = 1.f / lrun[mi];
        const size_t qg = rowbase + q0 + mi * 16 + m15;
#pragma unroll
        for (int i = 0; i < 4; ++i) {
            us4 o = { f2h(accO[mi][i][0] * li), f2h(accO[mi][i][1] * li),
                      f2h(accO[mi][i][2] * li), f2h(accO[mi][i][3] * li) };
            *(us4*)(ao + qg * D_MODEL + h * DK + i * 16 + g * 4) = o;
        }
    }
}

// ---------------------------------------------------------------------------
extern "C" void kernel_launch(void* const* d_in, const int* in_sizes, int n_in,
                              void* d_out, int out_size, void* d_ws, size_t ws_size,
                              hipStream_t stream)
{
    const float* Q  = (const float*)d_in[0];
    const float* K  = (const float*)d_in[1];
    const float* V  = (const float*)d_in[2];
    const float* Wq = (const float*)d_in[3];
    const float* Wk = (const float*)d_in[4];
    const float* Wv = (const float*)d_in[5];
    const float* Wo = (const float*)d_in[6];

    unsigned short* base = (unsigned short*)d_ws;
    unsigned short* qb = base;
    unsigned short* kb = qb + TENS;
    unsigned short* vb = kb + TENS;
    unsigned short* wq = vb + TENS;
    unsigned short* wk = wq + WELT;
    unsigned short* wv = wk + WELT;
    unsigned short* wo = wv + WELT;
    unsigned short* qproj = wo + WELT;
    unsigned short* kproj = qproj + TENS;
    unsigned short* vtw   = kproj + TENS;    // [B,H,S/8,DK,8] granule-interleaved
    unsigned short* aow   = vtw + TENS;

    convert_kernel<<<dim3(TENS / 1024, 4), 256, 0, stream>>>(Q, K, V, Wq, Wk, Wv, Wo, base);

    proj3_kernel<<<dim3(MROWS / 128, D_MODEL / 128, 3), 256, 0, stream>>>(
        qb, kb, vb, wq, wk, wv, qproj, kproj, vtw);

    attn_kernel<<<dim3(SEQ / 256, NHEADS, BATCH), 256, 0, stream>>>(
        qproj, kproj, vtw, aow);

    gemm_out_kernel<<<dim3(MROWS / 128, D_MODEL / 128), 256, 0, stream>>>(
        aow, wo, (float*)d_out);
}

// Round 4
// 329.619 us; speedup vs baseline: 1.0877x; 1.0444x over previous
//
#include <hip/hip_runtime.h>
#include <math.h>
#include <stdint.h>

#define D_MODEL 1024
#define NHEADS  16
#define DK      64
#define BATCH   4
#define SEQ     2048
#define MROWS   (BATCH * SEQ)              // 8192
#define TENS    ((size_t)MROWS * D_MODEL)  // 8.39M elems
#define WELT    ((size_t)D_MODEL * D_MODEL)

typedef __attribute__((ext_vector_type(8))) _Float16 f16x8;
typedef __attribute__((ext_vector_type(2))) __fp16 h16x2;
typedef __attribute__((ext_vector_type(4))) float f32x4;
typedef __attribute__((ext_vector_type(8))) unsigned short us8;
typedef __attribute__((ext_vector_type(4))) unsigned short us4;

__device__ __forceinline__ unsigned short f2h(float x) {
    _Float16 h = (_Float16)x;
    return __builtin_bit_cast(unsigned short, h);
}

#if __has_builtin(__builtin_amdgcn_exp2f)
__device__ __forceinline__ float fexp2(float x) { return __builtin_amdgcn_exp2f(x); }
#else
__device__ __forceinline__ float fexp2(float x) { return exp2f(x); }
#endif

// async global->LDS, 16B per lane; LDS dst is wave-uniform base + lane*16
__device__ __forceinline__ void gld_lds16(const void* g, void* l) {
    __builtin_amdgcn_global_load_lds(
        (__attribute__((address_space(1))) void*)(uintptr_t)(g),
        (__attribute__((address_space(3))) void*)(unsigned)(uintptr_t)(l),
        16, 0, 0);
}

// ---------------------------------------------------------------------------
// fp32 -> f16 conversion of all inputs into workspace.
// seg 0..2: Q/K/V tensors (TENS each). seg 3: all four weight matrices.
// ---------------------------------------------------------------------------
__global__ __launch_bounds__(256)
void convert_kernel(const float* __restrict__ q, const float* __restrict__ k,
                    const float* __restrict__ v, const float* __restrict__ wq,
                    const float* __restrict__ wk, const float* __restrict__ wv,
                    const float* __restrict__ wo, unsigned short* __restrict__ dst)
{
    const int seg = blockIdx.y;
    size_t i = ((size_t)blockIdx.x * 256 + threadIdx.x) * 4;
    const float* src;
    size_t doff, soff;
    if (seg < 3) {
        if (i >= TENS) return;
        src = (seg == 0) ? q : (seg == 1) ? k : v;
        soff = i;
        doff = (size_t)seg * TENS + i;
    } else {
        if (i >= 4 * WELT) return;
        const int widx = (int)(i >> 20);          // WELT == 1<<20
        src = (widx == 0) ? wq : (widx == 1) ? wk : (widx == 2) ? wv : wo;
        soff = i & (WELT - 1);
        doff = 3 * TENS + i;
    }
    float4 f = *(const float4*)(src + soff);
    us4 o = { f2h(f.x), f2h(f.y), f2h(f.z), f2h(f.w) };
    *(us4*)(dst + doff) = o;
}

// ---------------------------------------------------------------------------
// f16 MFMA NT GEMM: C[M,N] = A[M,K] @ B[N,K]^T
// 256x128 tile, 512 thr = 8 waves (4 row x 2 col, 64x64 each), BK=64.
// 3-deep LDS pipeline (144 KB): global_load_lds staged 2 tiles ahead,
// raw s_barrier with COUNTED s_waitcnt vmcnt(12/6/0) -- loads stay in
// flight across barriers (T3+T4), never drained to 0 in steady state.
// XOR-swizzled LDS (physical chunk c at row r holds logical chunk c^(r&7)).
// omode: 0 = fp32 row-major, 1 = f16 row-major,
//        2 = f16 V-transpose, granule-interleaved [b][h][s/8][d][s%8]
// ---------------------------------------------------------------------------
__device__ __forceinline__
void gemm_body8(const unsigned short* __restrict__ A,
                const unsigned short* __restrict__ B,
                void* __restrict__ C, int N, int K, int omode,
                unsigned short* As, unsigned short* Bs)
{
    const int tid  = threadIdx.x;
    const int wave = tid >> 6;
    const int lane = tid & 63;
    const int g    = lane >> 4;
    const int m15  = lane & 15;
    const int bm   = blockIdx.x * 256;
    const int bn   = blockIdx.y * 128;

    const int srw = lane >> 3;
    const int lc  = (lane & 7) ^ srw;

    const int wr = (wave >> 1) * 64;   // 4 row-waves
    const int wc = (wave & 1) * 64;    // 2 col-waves

    f32x4 acc[4][4];
#pragma unroll
    for (int i = 0; i < 4; ++i)
#pragma unroll
        for (int j = 0; j < 4; ++j) acc[i][j] = (f32x4){0.f, 0.f, 0.f, 0.f};

    // 6 gld_lds per wave per call (4 A-rounds + 2 B-rounds) -- vmcnt unit.
    auto stage = [&](int buf, int t) {
        const int k0 = t * 64;
#pragma unroll
        for (int i = 0; i < 4; ++i) {
            const int rb = i * 64 + wave * 8;
            gld_lds16(A + (size_t)(bm + rb + srw) * K + k0 + lc * 8,
                      &As[buf * (256 * 64) + rb * 64]);
        }
#pragma unroll
        for (int j = 0; j < 2; ++j) {
            const int rb = j * 64 + wave * 8;
            gld_lds16(B + (size_t)(bn + rb + srw) * K + k0 + lc * 8,
                      &Bs[buf * (128 * 64) + rb * 64]);
        }
    };

    auto compute = [&](int buf) {
        const unsigned short* Ab = &As[buf * (256 * 64)];
        const unsigned short* Bb = &Bs[buf * (128 * 64)];
#pragma unroll
        for (int t = 0; t < 2; ++t) {
            f16x8 af[4], bf[4];
#pragma unroll
            for (int i = 0; i < 4; ++i) {
                int row = wr + i * 16 + m15;
                int pc  = (4 * t + g) ^ (row & 7);
                af[i] = *(const f16x8*)&Ab[row * 64 + pc * 8];
            }
#pragma unroll
            for (int j = 0; j < 4; ++j) {
                int row = wc + j * 16 + m15;
                int pc  = (4 * t + g) ^ (row & 7);
                bf[j] = *(const f16x8*)&Bb[row * 64 + pc * 8];
            }
            __builtin_amdgcn_s_setprio(1);
#pragma unroll
            for (int i = 0; i < 4; ++i)
#pragma unroll
                for (int j = 0; j < 4; ++j)
                    acc[i][j] = __builtin_amdgcn_mfma_f32_16x16x32_f16(
                        af[i], bf[j], acc[i][j], 0, 0, 0);
            __builtin_amdgcn_s_setprio(0);
        }
    };

    const int NT = K / 64;   // 16
    stage(0, 0);
    stage(1, 1);
    int cur = 0;
    for (int t = 0; t < NT; ++t) {
        if (t + 2 < NT) {
            int nb = cur + 2; if (nb >= 3) nb -= 3;
            stage(nb, t + 2);
            // tile t's 6 loads are the oldest of <=18 outstanding
            asm volatile("s_waitcnt vmcnt(12)" ::: "memory");
        } else if (t + 1 < NT) {
            asm volatile("s_waitcnt vmcnt(6)" ::: "memory");
        } else {
            asm volatile("s_waitcnt vmcnt(0)" ::: "memory");
        }
        __builtin_amdgcn_s_barrier();            // tile t fully in LDS for all waves
        __builtin_amdgcn_sched_barrier(0);       // no ds_read hoists above barrier
        compute(cur);
        __builtin_amdgcn_sched_barrier(0);       // no ds_read sinks below barrier
        __builtin_amdgcn_s_barrier();            // all waves done reading buf cur
        ++cur; if (cur == 3) cur = 0;
    }

#pragma unroll
    for (int i = 0; i < 4; ++i) {
        const int gm0 = bm + wr + i * 16 + g * 4;
#pragma unroll
        for (int j = 0; j < 4; ++j) {
            const int gn = bn + wc + j * 16 + m15;
            if (omode == 0) {
#pragma unroll
                for (int r = 0; r < 4; ++r)
                    ((float*)C)[(size_t)(gm0 + r) * N + gn] = acc[i][j][r];
            } else if (omode == 1) {
#pragma unroll
                for (int r = 0; r < 4; ++r)
                    ((unsigned short*)C)[(size_t)(gm0 + r) * N + gn] = f2h(acc[i][j][r]);
            } else {
                const int b_ = gm0 >> 11, s_ = gm0 & 2047;
                const int h_ = gn >> 6,  d_ = gn & 63;
                us4 o = { f2h(acc[i][j][0]), f2h(acc[i][j][1]),
                          f2h(acc[i][j][2]), f2h(acc[i][j][3]) };
                // [b][h][s>>3][d][s&7]; s_&7 in {0,4} so the us4 is 8B-aligned
                *(us4*)((unsigned short*)C +
                        (((size_t)(b_ * NHEADS + h_) * 256 + (s_ >> 3)) * 64 + d_) * 8
                        + (s_ & 7)) = o;
            }
        }
    }
}

// Fused Q/K/V projections in one dispatch: blockIdx.z selects the GEMM.
__global__ __launch_bounds__(512)
void proj3_kernel(const unsigned short* __restrict__ qb,
                  const unsigned short* __restrict__ kb,
                  const unsigned short* __restrict__ vb,
                  const unsigned short* __restrict__ wq,
                  const unsigned short* __restrict__ wk,
                  const unsigned short* __restrict__ wv,
                  unsigned short* __restrict__ qproj,
                  unsigned short* __restrict__ kproj,
                  unsigned short* __restrict__ vtw)
{
    __shared__ unsigned short As[3 * 256 * 64];   // 96 KB
    __shared__ unsigned short Bs[3 * 128 * 64];   // 48 KB
    const int z = blockIdx.z;
    const unsigned short* A = (z == 0) ? qb : (z == 1) ? kb : vb;
    const unsigned short* B = (z == 0) ? wq : (z == 1) ? wk : wv;
    void* C = (z == 0) ? (void*)qproj : (z == 1) ? (void*)kproj : (void*)vtw;
    gemm_body8(A, B, C, D_MODEL, D_MODEL, (z == 2) ? 2 : 1, As, Bs);
}

__global__ __launch_bounds__(512)
void gemm_out_kernel(const unsigned short* __restrict__ A,
                     const unsigned short* __restrict__ B,
                     float* __restrict__ C)
{
    __shared__ unsigned short As[3 * 256 * 64];
    __shared__ unsigned short Bs[3 * 128 * 64];
    gemm_body8(A, B, C, D_MODEL, D_MODEL, 0, As, Bs);
}

// ---------------------------------------------------------------------------
// Flash attention, transposed-score form, 64 q/wave (mi=4), 2-phase pipeline.
// (unchanged from round 3 -- control for this round's GEMM change)
// ---------------------------------------------------------------------------
__global__ __launch_bounds__(256, 2)
void attn_kernel(const unsigned short* __restrict__ qp,
                 const unsigned short* __restrict__ kp,
                 const unsigned short* __restrict__ vt,
                 unsigned short* __restrict__ ao)
{
    __shared__ unsigned short Ks[2][64 * 64];   // [buf][key][d], XOR-swizzled
    __shared__ unsigned short VTs[2][64 * 64];  // [buf][d][key], XOR-swizzled
    __shared__ unsigned short Ps[4][16 * 72];   // per-wave P^T, one mi at a time

    const int tid = threadIdx.x;
    const int w = tid >> 6, lane = tid & 63;
    const int g = lane >> 4, m15 = lane & 15;
    const int qt = blockIdx.x, h = blockIdx.y, b = blockIdx.z;

    const int q0 = qt * 256 + w * 64;
    const size_t rowbase = (size_t)b * SEQ;

    const int srw = lane >> 3;
    const int lc  = (lane & 7) ^ srw;

    // Q fragments (B-operand), pre-scaled by (1/sqrt(dk)) * log2(e)
    const _Float16 qscale = (_Float16)(0.125f * 1.4426950408889634f);
    f16x8 qf[4][2];
#pragma unroll
    for (int mi = 0; mi < 4; ++mi)
#pragma unroll
        for (int t = 0; t < 2; ++t) {
            f16x8 v = *(const f16x8*)(qp + (rowbase + q0 + mi * 16 + m15) * D_MODEL
                                      + h * DK + t * 32 + g * 8);
            qf[mi][t] = v * qscale;
        }

    const _Float16 one16 = (_Float16)1.f;
    const f16x8 onesf = { one16, one16, one16, one16, one16, one16, one16, one16 };

    float mrun[4] = {-INFINITY, -INFINITY, -INFINITY, -INFINITY};
    float lrun[4] = {0.f, 0.f, 0.f, 0.f};

    f32x4 accO[4][4];
#pragma unroll
    for (int mi = 0; mi < 4; ++mi)
#pragma unroll
        for (int i = 0; i < 4; ++i) accO[mi][i] = (f32x4){0.f, 0.f, 0.f, 0.f};

    const unsigned short* kbase = kp + rowbase * D_MODEL + h * DK;
    const unsigned short* vbase = vt + (size_t)(b * NHEADS + h) * DK * SEQ;

    auto stage = [&](int buf, int t) {
#pragma unroll
        for (int it = 0; it < 2; ++it) {
            const int rb = w * 16 + it * 8;
            gld_lds16(kbase + (size_t)(t * 64 + rb + srw) * D_MODEL + lc * 8,
                      &Ks[buf][rb * 64]);
            // vt granule layout: elem = (s8*64 + d)*8 + (s&7); 16B = 8 s for one d
            gld_lds16(vbase + ((size_t)(t * 8 + lc) * 64 + rb + srw) * 8,
                      &VTs[buf][rb * 64]);
        }
    };

    const int NT = SEQ / 64;
    stage(0, 0);
    __syncthreads();   // compiler-emitted vmcnt(0) drains prologue loads

    for (int kt = 0; kt < NT; ++kt) {
        const int cur = kt & 1;
        if (kt + 1 < NT) stage(cur ^ 1, kt + 1);   // prefetch overlaps compute below

        // S^T (log2 domain): ST[km][mi] reg r: key=km*16+g*4+r, q=mi*16+m15
        f32x4 ST[4][4];
        __builtin_amdgcn_s_setprio(1);
#pragma unroll
        for (int km = 0; km < 4; ++km) {
            const int row = km * 16 + m15;
            f16x8 kf0 = *(const f16x8*)&Ks[cur][row * 64 + ((0 + g) ^ (row & 7)) * 8];
            f16x8 kf1 = *(const f16x8*)&Ks[cur][row * 64 + ((4 + g) ^ (row & 7)) * 8];
#pragma unroll
            for (int mi = 0; mi < 4; ++mi) {
                f32x4 z = (f32x4){0.f, 0.f, 0.f, 0.f};
                z = __builtin_amdgcn_mfma_f32_16x16x32_f16(kf0, qf[mi][0], z, 0, 0, 0);
                z = __builtin_amdgcn_mfma_f32_16x16x32_f16(kf1, qf[mi][1], z, 0, 0, 0);
                ST[km][mi] = z;
            }
        }
        __builtin_amdgcn_s_setprio(0);

        // register-resident online softmax in log2 domain (q = mi*16+m15).
        // max via v_max3-fusable triples; denominator via ones-MFMA below.
        float scl[4];
        f16x8 pf[4][2];
#pragma unroll
        for (int mi = 0; mi < 4; ++mi) {
            float t0 = fmaxf(fmaxf(ST[0][mi][0], ST[0][mi][1]), ST[0][mi][2]);
            float t1 = fmaxf(fmaxf(ST[0][mi][3], ST[1][mi][0]), ST[1][mi][1]);
            float t2 = fmaxf(fmaxf(ST[1][mi][2], ST[1][mi][3]), ST[2][mi][0]);
            float t3 = fmaxf(fmaxf(ST[2][mi][1], ST[2][mi][2]), ST[2][mi][3]);
            float t4 = fmaxf(fmaxf(ST[3][mi][0], ST[3][mi][1]), ST[3][mi][2]);
            float u0 = fmaxf(fmaxf(t0, t1), t2);
            float u1 = fmaxf(fmaxf(t3, t4), ST[3][mi][3]);
            float mx = fmaxf(u0, u1);
            mx = fmaxf(mx, __shfl_xor(mx, 16));
            mx = fmaxf(mx, __shfl_xor(mx, 32));
            float mnew = fmaxf(mrun[mi], mx);
            scl[mi] = fexp2(mrun[mi] - mnew);
            mrun[mi] = mnew;
#pragma unroll
            for (int km = 0; km < 4; ++km) {
                float p0 = fexp2(ST[km][mi][0] - mnew);
                float p1 = fexp2(ST[km][mi][1] - mnew);
                float p2 = fexp2(ST[km][mi][2] - mnew);
                float p3 = fexp2(ST[km][mi][3] - mnew);
                h16x2 d0 = __builtin_amdgcn_cvt_pkrtz(p0, p1);
                h16x2 d1 = __builtin_amdgcn_cvt_pkrtz(p2, p3);
                uint2 wv = { __builtin_bit_cast(unsigned, d0),
                             __builtin_bit_cast(unsigned, d1) };
                *(uint2*)&Ps[w][m15 * 72 + km * 16 + g * 4] = wv;
            }
            // read back this mi's P^T fragments (in-order LDS FIFO: safe)
            pf[mi][0] = *(const f16x8*)&Ps[w][m15 * 72 + g * 8];
            pf[mi][1] = *(const f16x8*)&Ps[w][m15 * 72 + 32 + g * 8];
            // denominator on the matrix pipe: C[i][q=m15] = sum_k P^T[q][k]
            f32x4 zs = (f32x4){0.f, 0.f, 0.f, 0.f};
            zs = __builtin_amdgcn_mfma_f32_16x16x32_f16(onesf, pf[mi][0], zs, 0, 0, 0);
            zs = __builtin_amdgcn_mfma_f32_16x16x32_f16(onesf, pf[mi][1], zs, 0, 0, 0);
            lrun[mi] = lrun[mi] * scl[mi] + zs[0];
        }

        // wave-uniform skip of accO rescale when max didn't move anywhere
        int chg = (scl[0] < 1.f) | (scl[1] < 1.f) | (scl[2] < 1.f) | (scl[3] < 1.f);
        if (__any(chg)) {
#pragma unroll
            for (int mi = 0; mi < 4; ++mi)
#pragma unroll
                for (int i = 0; i < 4; ++i) accO[mi][i] *= scl[mi];
        }

        // O^T += V^T·P^T
        __builtin_amdgcn_s_setprio(1);
#pragma unroll
        for (int i = 0; i < 4; ++i) {
            const int row = i * 16 + m15;
            f16x8 vf0 = *(const f16x8*)&VTs[cur][row * 64 + ((0 + g) ^ (row & 7)) * 8];
            f16x8 vf1 = *(const f16x8*)&VTs[cur][row * 64 + ((4 + g) ^ (row & 7)) * 8];
#pragma unroll
            for (int mi = 0; mi < 4; ++mi) {
                f32x4 a = accO[mi][i];
                a = __builtin_amdgcn_mfma_f32_16x16x32_f16(vf0, pf[mi][0], a, 0, 0, 0);
                a = __builtin_amdgcn_mfma_f32_16x16x32_f16(vf1, pf[mi][1], a, 0, 0, 0);
                accO[mi][i] = a;
            }
        }
        __builtin_amdgcn_s_setprio(0);

        __syncthreads();   // drains vmcnt(0) (prefetch done) + protects buffer reuse
    }

    // epilogue: O^T row d=i*16+g*4+r, col q=mi*16+m15 -> ao[b][s][h*64+d]
#pragma unroll
    for (int mi = 0; mi < 4; ++mi) {
        const float li = 1.f / lrun[mi];
        const size_t qg = rowbase + q0 + mi * 16 + m15;
#pragma unroll
        for (int i = 0; i < 4; ++i) {
            us4 o = { f2h(accO[mi][i][0] * li), f2h(accO[mi][i][1] * li),
                      f2h(accO[mi][i][2] * li), f2h(accO[mi][i][3] * li) };
            *(us4*)(ao + qg * D_MODEL + h * DK + i * 16 + g * 4) = o;
        }
    }
}

// ---------------------------------------------------------------------------
extern "C" void kernel_launch(void* const* d_in, const int* in_sizes, int n_in,
                              void* d_out, int out_size, void* d_ws, size_t ws_size,
                              hipStream_t stream)
{
    const float* Q  = (const float*)d_in[0];
    const float* K  = (const float*)d_in[1];
    const float* V  = (const float*)d_in[2];
    const float* Wq = (const float*)d_in[3];
    const float* Wk = (const float*)d_in[4];
    const float* Wv = (const float*)d_in[5];
    const float* Wo = (const float*)d_in[6];

    unsigned short* base = (unsigned short*)d_ws;
    unsigned short* qb = base;
    unsigned short* kb = qb + TENS;
    unsigned short* vb = kb + TENS;
    unsigned short* wq = vb + TENS;
    unsigned short* wk = wq + WELT;
    unsigned short* wv = wk + WELT;
    unsigned short* wo = wv + WELT;
    unsigned short* qproj = wo + WELT;
    unsigned short* kproj = qproj + TENS;
    unsigned short* vtw   = kproj + TENS;    // [B,H,S/8,DK,8] granule-interleaved
    unsigned short* aow   = vtw + TENS;

    convert_kernel<<<dim3(TENS / 1024, 4), 256, 0, stream>>>(Q, K, V, Wq, Wk, Wv, Wo, base);

    proj3_kernel<<<dim3(MROWS / 256, D_MODEL / 128, 3), 512, 0, stream>>>(
        qb, kb, vb, wq, wk, wv, qproj, kproj, vtw);

    attn_kernel<<<dim3(SEQ / 256, NHEADS, BATCH), 256, 0, stream>>>(
        qproj, kproj, vtw, aow);

    gemm_out_kernel<<<dim3(MROWS / 256, D_MODEL / 128), 512, 0, stream>>>(
        aow, wo, (float*)d_out);
}